// Round 7
// baseline (827.363 us; speedup 1.0000x reference)
//
#include <hip/hip_runtime.h>

#define Q_DIM 21
#define BLKB  1764          // bytes per 21x21 J block
#define WINB  1792          // staged J window (16B-aligned superset)
#define SLOT  2304          // WINB + 512B idx
#define NBUF  6             // ring: write-after-read distance = 3 barriers
#define DEPTH 3             // stage col j+DEPTH; wait vmcnt(3)
#define CH    32            // j-chunk length
#define NQ    1145          // chunks per m-half = sum_i max(1,ceil(i/32))
#define GRIDH 1152          // padded half-grid (multiple of 8 -> mh pair same XCD)

#define GLD(src, dst, sz) __builtin_amdgcn_global_load_lds( \
    (const __attribute__((address_space(1))) void*)(src),   \
    (__attribute__((address_space(3))) void*)(dst), sz, 0, 0)

// ---- prep: one-hot -> u16 byte-offset table  Xt[j*512 + m] = 84 * argmax ----
__global__ __launch_bounds__(64) void ardca_prep(const float* __restrict__ X_oh,
                                                 unsigned short* __restrict__ Xt) {
  int w = blockIdx.x;
  int lane = threadIdx.x;
  const float* base = X_oh + (size_t)w * (32 * Q_DIM);   // 672 floats
  int rowbase = w * 32;                                  // row id = m*256 + j
#pragma unroll
  for (int p = 0; p < 11; ++p) {
    int f = p * 63 + lane;
    float v = (lane < 63 && f < 672) ? base[f] : 0.0f;
    unsigned long long mask = __ballot(v > 0.5f);
    if (lane < 3) {
      int rloc = 3 * p + lane;
      if (rloc < 32) {
        unsigned int bits = (unsigned int)((mask >> (21 * lane)) & 0x1FFFFFu);
        int x = bits ? __builtin_ctz(bits) : 0;
        int rr = rowbase + rloc;
        int m = rr >> 8, j = rr & 255;
        Xt[j * 512 + m] = (unsigned short)(x * 84);
      }
    }
  }
}

// ---- main: out[m,i,a] += sum_{j in chunk} J[i,j,x_mj,a]  (+h if first chunk) ----
// blocks = (i, mh, c): 32-j chunks, atomicAdd into zeroed out. 512 thr = 256m x 2ah.
template <int USE_XT>
__global__ __launch_bounds__(512, 8) void ardca_main(const float* __restrict__ Jm,
                                                     const float* __restrict__ h,
                                                     const unsigned short* __restrict__ Xt,
                                                     const float* __restrict__ X_oh,
                                                     float* __restrict__ out) {
  alignas(16) __shared__ char lds[NBUF * SLOT];          // 13824 B
  int b = blockIdx.x;
  int mh = (b >= GRIDH) ? 1 : 0;
  int q = b - mh * GRIDH;
  if (q >= NQ) return;
  // decode q -> (i, c); group g has i in [32g+1-(g==0), 32(g+1)], (g+1) chunks each
  int g, r;
  if      (q <  33) { g = 0; r = q;       }
  else if (q <  97) { g = 1; r = q - 33;  }
  else if (q < 193) { g = 2; r = q - 97;  }
  else if (q < 321) { g = 3; r = q - 193; }
  else if (q < 481) { g = 4; r = q - 321; }
  else if (q < 673) { g = 5; r = q - 481; }
  else if (q < 897) { g = 6; r = q - 673; }
  else              { g = 7; r = q - 897; }
  int i, c;
  switch (g) {
    case 0:  i = r;              c = 0;     break;
    case 1:  i = 33  + (r >> 1); c = r & 1; break;
    case 2:  i = 65  + r / 3;    c = r % 3; break;
    case 3:  i = 97  + (r >> 2); c = r & 3; break;
    case 4:  i = 129 + r / 5;    c = r % 5; break;
    case 5:  i = 161 + r / 6;    c = r % 6; break;
    case 6:  i = 193 + r / 7;    c = r % 7; break;
    default: i = 225 + (r >> 3); c = r & 7; break;
  }
  int jlo = c * CH;
  int jhi = jlo + CH; if (jhi > i) jhi = i;

  int tid = threadIdx.x;
  int ml = tid & 255;            // m within half
  int ah = tid >> 8;             // 0 -> floats 0..11, 1 -> floats 12..20
  int m = mh * 256 + ml;

  const char* Jrow = (const char*)Jm + (size_t)i * (256ull * BLKB);
  const char* XtB  = (const char*)Xt;

  float acc[12];
  if (c == 0) {
    const float* hp = h + i * Q_DIM + ah * 12;
#pragma unroll
    for (int k = 0; k < 12; ++k) acc[k] = (k < 9 || ah == 0) ? hp[k] : 0.0f;
  } else {
#pragma unroll
    for (int k = 0; k < 12; ++k) acc[k] = 0.0f;
  }

  auto STAGE = [&](int j) {
    char* buf = lds + (j % NBUF) * SLOT;
    unsigned bb = (unsigned)j * BLKB;
    const char* src = Jrow + (bb & ~15u);                // 16B-aligned window
    if (tid < 112) GLD(src + tid * 16, buf + tid * 16, 16);      // 1792 B J
    if (USE_XT) {
      if (tid >= 128 && tid < 160)                       // 512 B idx (256 u16)
        GLD(XtB + j * 1024 + mh * 512 + (tid - 128) * 16,
            buf + WINB + (tid - 128) * 16, 16);
    }
  };

  auto CONSUME = [&](int j) {
    const char* buf = lds + (j % NBUF) * SLOT;
    int off;
    if (USE_XT) {
      off = *(const unsigned short*)(buf + WINB + 2 * ml);       // 84*x, staged
    } else {
      const float* p = X_oh + ((size_t)m * 256 + j) * Q_DIM;
      int x = 0;
#pragma unroll
      for (int a = 0; a < Q_DIM; ++a) x = (p[a] > 0.5f) ? a : x;
      off = x * 84;
    }
    // window misalignment delta: (j*1764) & 15 == (j&3)*4
    const float* row = (const float*)(buf + ((j & 3) << 2) + off + ah * 48);
#pragma unroll
    for (int k = 0; k < 12; ++k)
      if (ah == 0 || k < 9) acc[k] += row[k];            // 84B per m exact
  };

  int P = jhi - jlo; if (P > DEPTH) P = DEPTH;
  for (int j = jlo; j < jlo + P; ++j) STAGE(j);
  int jt = jhi - DEPTH; if (jt < jlo) jt = jlo;

#pragma unroll 1
  for (int j = jlo; j < jt; ++j) {
    STAGE(j + DEPTH);
    if (USE_XT) asm volatile("s_waitcnt vmcnt(3)" ::: "memory");  // counted, never 0
    else        asm volatile("s_waitcnt vmcnt(0)" ::: "memory");
    __builtin_amdgcn_sched_barrier(0);
    __builtin_amdgcn_s_barrier();
    CONSUME(j);
  }
  asm volatile("s_waitcnt vmcnt(0)" ::: "memory");
  __builtin_amdgcn_sched_barrier(0);
  __builtin_amdgcn_s_barrier();
#pragma unroll 1
  for (int j = jt; j < jhi; ++j) CONSUME(j);

  float* o = out + ((size_t)m * 256 + i) * Q_DIM + ah * 12;
#pragma unroll
  for (int k = 0; k < 12; ++k)
    if (ah == 0 || k < 9) unsafeAtomicAdd(&o[k], acc[k]);
}

extern "C" void kernel_launch(void* const* d_in, const int* in_sizes, int n_in,
                              void* d_out, int out_size, void* d_ws, size_t ws_size,
                              hipStream_t stream) {
  const float* X_oh = (const float*)d_in[0];
  const float* h    = (const float*)d_in[1];
  const float* Jm   = (const float*)d_in[2];
  float* out        = (float*)d_out;
  unsigned short* Xt = (unsigned short*)d_ws;            // 262144 B

  hipMemsetAsync(d_out, 0, (size_t)out_size * sizeof(float), stream);
  if (ws_size >= 262144) {
    ardca_prep<<<4096, 64, 0, stream>>>(X_oh, Xt);
    ardca_main<1><<<2 * GRIDH, 512, 0, stream>>>(Jm, h, Xt, X_oh, out);
  } else {
    ardca_main<0><<<2 * GRIDH, 512, 0, stream>>>(Jm, h, Xt, X_oh, out);
  }
}

// Round 8
// 216.974 us; speedup vs baseline: 3.8132x; 3.8132x over previous
//
#include <hip/hip_runtime.h>

#define Q_DIM 21
#define BLKB  1764          // bytes per 21x21 J block
#define WINB  1792          // staged J window (16B-aligned superset)
#define SLOT  2304          // WINB + 512B idx
#define NBUF  16            // ring: slots j..j+12 live = 13 <= 16 (AND addressing)
#define DEPTH 12            // stage col j+DEPTH; wait vmcnt(12): latency/12 ~ 75cy < LDS 186cy

#define GLD(src, dst, sz) __builtin_amdgcn_global_load_lds( \
    (const __attribute__((address_space(1))) void*)(src),   \
    (__attribute__((address_space(3))) void*)(dst), sz, 0, 0)

// ---- prep: one-hot -> u16 byte-offset table  Xt[j*512 + m] = 84 * argmax ----
__global__ __launch_bounds__(64) void ardca_prep(const float* __restrict__ X_oh,
                                                 unsigned short* __restrict__ Xt) {
  int w = blockIdx.x;
  int lane = threadIdx.x;
  const float* base = X_oh + (size_t)w * (32 * Q_DIM);   // 672 floats
  int rowbase = w * 32;                                  // row id = m*256 + j
#pragma unroll
  for (int p = 0; p < 11; ++p) {
    int f = p * 63 + lane;
    float v = (lane < 63 && f < 672) ? base[f] : 0.0f;
    unsigned long long mask = __ballot(v > 0.5f);
    if (lane < 3) {
      int rloc = 3 * p + lane;
      if (rloc < 32) {
        unsigned int bits = (unsigned int)((mask >> (21 * lane)) & 0x1FFFFFu);
        int x = bits ? __builtin_ctz(bits) : 0;
        int rr = rowbase + rloc;
        int m = rr >> 8, j = rr & 255;
        Xt[j * 512 + m] = (unsigned short)(x * 84);
      }
    }
  }
}

// ---- main: out[m,i,a] = h[i,a] + sum_{j<i} J[i,j,x_mj,a] ----
// 512 blocks x 512 threads: block=(i, m-half); J staged ONCE per block (G=2).
// Sum-pairing (i1+i2~255 per CU) equalizes per-CU LDS work; ring-16 DEPTH-12
// counted-vmcnt pipeline hides load latency under the ~186cy/iter LDS floor.
template <int USE_XT>
__global__ __launch_bounds__(512, 4) void ardca_main(const float* __restrict__ Jm,
                                                     const float* __restrict__ h,
                                                     const unsigned short* __restrict__ Xt,
                                                     const float* __restrict__ X_oh,
                                                     float* __restrict__ out) {
  alignas(16) __shared__ char lds[NBUF * SLOT];          // 36864 B -> 2 blocks/CU
  int b = blockIdx.x;
  int i, mh;
  if (b < 256) { i = b; mh = 0; }                        // i == b (mod 8) -> XCD b%8
  else { int x = b - 256; i = 248 - (x & ~7) + (x & 7); mh = 1; }  // pair sum ~255, same XCD
  int tid = threadIdx.x;
  int ml = tid & 255;            // m within half
  int ah = tid >> 8;             // 0 -> floats 0..11, 1 -> floats 12..20 (wave-uniform)
  int m = mh * 256 + ml;

  const char* Jrow = (const char*)Jm + (size_t)i * (256ull * BLKB);
  const char* XtB  = (const char*)Xt;

  const float* hp = h + i * Q_DIM + ah * 12;
  float acc[12];
#pragma unroll
  for (int k = 0; k < 12; ++k)
    acc[k] = (k < 9 || ah == 0) ? hp[k] : 0.0f;          // guard h OOB at i=255,ah=1

  auto STAGE = [&](int j) {
    char* buf = lds + (j & (NBUF - 1)) * SLOT;
    unsigned bb = (unsigned)j * BLKB;
    const char* src = Jrow + (bb & ~15u);                // 16B-aligned window
    if (tid < 112) GLD(src + tid * 16, buf + tid * 16, 16);      // 1792 B J
    if (USE_XT) {
      if (tid >= 128 && tid < 160)                       // 512 B idx (256 u16)
        GLD(XtB + j * 1024 + mh * 512 + (tid - 128) * 16,
            buf + WINB + (tid - 128) * 16, 16);
    }
  };

  auto CONSUME = [&](int j) {
    const char* buf = lds + (j & (NBUF - 1)) * SLOT;
    int off;
    if (USE_XT) {
      off = *(const unsigned short*)(buf + WINB + 2 * ml);       // 84*x, staged
    } else {
      const float* p = X_oh + ((size_t)m * 256 + j) * Q_DIM;
      int x = 0;
#pragma unroll
      for (int a = 0; a < Q_DIM; ++a) x = (p[a] > 0.5f) ? a : x;
      off = x * 84;
    }
    // window misalignment delta: (j*1764) & 15 == (j&3)*4
    const float* row = (const float*)(buf + ((j & 3) << 2) + off + ah * 48);
#pragma unroll
    for (int k = 0; k < 12; ++k)
      if (ah == 0 || k < 9) acc[k] += row[k];            // 84B per m exact
  };

  int P = (i < DEPTH) ? i : DEPTH;
  for (int j = 0; j < P; ++j) STAGE(j);
  int jt = i - DEPTH; if (jt < 0) jt = 0;

#pragma unroll 1
  for (int j = 0; j < jt; ++j) {
    STAGE(j + DEPTH);
    if (USE_XT) asm volatile("s_waitcnt vmcnt(12)" ::: "memory"); // counted, never 0
    else        asm volatile("s_waitcnt vmcnt(0)" ::: "memory");
    __builtin_amdgcn_sched_barrier(0);
    __builtin_amdgcn_s_barrier();                        // raw: no vmcnt drain
    CONSUME(j);
  }
  asm volatile("s_waitcnt vmcnt(0)" ::: "memory");
  __builtin_amdgcn_sched_barrier(0);
  __builtin_amdgcn_s_barrier();
#pragma unroll 1
  for (int j = jt; j < i; ++j) CONSUME(j);

  float* o = out + ((size_t)m * 256 + i) * Q_DIM + ah * 12;
  if (ah == 0) {
#pragma unroll
    for (int k = 0; k < 12; ++k) o[k] = acc[k];
  } else {
#pragma unroll
    for (int k = 0; k < 9; ++k) o[k] = acc[k];
  }
}

extern "C" void kernel_launch(void* const* d_in, const int* in_sizes, int n_in,
                              void* d_out, int out_size, void* d_ws, size_t ws_size,
                              hipStream_t stream) {
  const float* X_oh = (const float*)d_in[0];
  const float* h    = (const float*)d_in[1];
  const float* Jm   = (const float*)d_in[2];
  float* out        = (float*)d_out;
  unsigned short* Xt = (unsigned short*)d_ws;            // 262144 B

  if (ws_size >= 262144) {
    ardca_prep<<<4096, 64, 0, stream>>>(X_oh, Xt);
    ardca_main<1><<<512, 512, 0, stream>>>(Jm, h, Xt, X_oh, out);
  } else {
    ardca_main<0><<<512, 512, 0, stream>>>(Jm, h, Xt, X_oh, out);
  }
}

// Round 9
// 209.587 us; speedup vs baseline: 3.9476x; 1.0352x over previous
//
#include <hip/hip_runtime.h>

#define Q_DIM 21
#define BLKB  1764          // bytes per 21x21 J block
#define WINB  1792          // staged J window (16B-aligned superset)
#define SLOT  2304          // WINB + 512B idx
#define NBUF  16            // ring slots (AND addressing); <=16 live at any time
#define AHEAD 12            // stage-ahead distance (js); vmcnt(12) exact in-loop

#define GLD(src, dst, sz) __builtin_amdgcn_global_load_lds( \
    (const __attribute__((address_space(1))) void*)(src),   \
    (__attribute__((address_space(3))) void*)(dst), sz, 0, 0)

// ---- prep: one-hot -> u16 byte-offset table  Xt[j*512 + m] = 84 * argmax ----
__global__ __launch_bounds__(64) void ardca_prep(const float* __restrict__ X_oh,
                                                 unsigned short* __restrict__ Xt) {
  int w = blockIdx.x;
  int lane = threadIdx.x;
  const float* base = X_oh + (size_t)w * (32 * Q_DIM);   // 672 floats
  int rowbase = w * 32;                                  // row id = m*256 + j
#pragma unroll
  for (int p = 0; p < 11; ++p) {
    int f = p * 63 + lane;
    float v = (lane < 63 && f < 672) ? base[f] : 0.0f;
    unsigned long long mask = __ballot(v > 0.5f);
    if (lane < 3) {
      int rloc = 3 * p + lane;
      if (rloc < 32) {
        unsigned int bits = (unsigned int)((mask >> (21 * lane)) & 0x1FFFFFu);
        int x = bits ? __builtin_ctz(bits) : 0;
        int rr = rowbase + rloc;
        int m = rr >> 8, j = rr & 255;
        Xt[j * 512 + m] = (unsigned short)(x * 84);
      }
    }
  }
}

// ---- main: out[m,i,a] = h[i,a] + sum_{j<i} J[i,j,x_mj,a] ----
// 512 blocks x 256 threads (4 waves): block=(i, m-half), lane = one m, 21 floats.
// Grouped-4 consume per barrier; stage-ahead 12; counted vmcnt(12); ring-16.
template <int USE_XT>
__global__ __launch_bounds__(256, 2) void ardca_main(const float* __restrict__ Jm,
                                                     const float* __restrict__ h,
                                                     const unsigned short* __restrict__ Xt,
                                                     const float* __restrict__ X_oh,
                                                     float* __restrict__ out) {
  alignas(16) __shared__ char lds[NBUF * SLOT];          // 36864 B
  int b = blockIdx.x;
  int i, mh;
  if (b < 256) { i = b; mh = 0; }                        // i == b (mod 8) -> XCD b%8
  else { int x = b - 256; i = 248 - (x & ~7) + (x & 7); mh = 1; }  // pair sum ~255, same XCD
  int tid = threadIdx.x;                                 // = m within half
  int m = mh * 256 + tid;

  const char* Jrow = (const char*)Jm + (size_t)i * (256ull * BLKB);
  const char* XtB  = (const char*)Xt;

  float acc[Q_DIM];
#pragma unroll
  for (int k = 0; k < Q_DIM; ++k) acc[k] = 0.0f;

  auto STAGE = [&](int j) {
    char* buf = lds + (j & (NBUF - 1)) * SLOT;
    unsigned bb = (unsigned)j * BLKB;
    const char* src = Jrow + (bb & ~15u);                // 16B-aligned window
    if (tid < 112) GLD(src + tid * 16, buf + tid * 16, 16);      // 1792 B J (waves 0,1)
    if (USE_XT) {
      if (tid >= 128 && tid < 160)                       // 512 B idx (wave 2)
        GLD(XtB + j * 1024 + mh * 512 + (tid - 128) * 16,
            buf + WINB + (tid - 128) * 16, 16);
    }
  };

  auto OFF = [&](int j) -> int {
    const char* buf = lds + (j & (NBUF - 1)) * SLOT;
    if (USE_XT) return *(const unsigned short*)(buf + WINB + 2 * tid);   // 84*x
    const float* p = X_oh + ((size_t)m * 256 + j) * Q_DIM;
    int x = 0;
#pragma unroll
    for (int a = 0; a < Q_DIM; ++a) x = (p[a] > 0.5f) ? a : x;
    return x * 84;
  };

  auto GATHER = [&](int j, int off) {
    const char* buf = lds + (j & (NBUF - 1)) * SLOT;
    // window misalignment delta: (j*1764) & 15 == (j&3)*4
    const float* row = (const float*)(buf + ((j & 3) << 2) + off);
#pragma unroll
    for (int k = 0; k < Q_DIM; ++k) acc[k] += row[k];    // 10x ds_read2_b32 + 1x b32
  };

  int pre = (i < AHEAD) ? i : AHEAD;
  for (int j = 0; j < pre; ++j) STAGE(j);

  int jb = 0;
#pragma unroll 1
  for (; jb + 15 < i; jb += 4) {
    STAGE(jb + 12); STAGE(jb + 13); STAGE(jb + 14); STAGE(jb + 15);
    if (USE_XT) asm volatile("s_waitcnt vmcnt(12)" ::: "memory");  // counted, never 0
    else        asm volatile("s_waitcnt vmcnt(0)" ::: "memory");
    __builtin_amdgcn_sched_barrier(0);
    __builtin_amdgcn_s_barrier();                        // raw: no vmcnt drain
    int o0 = OFF(jb), o1 = OFF(jb + 1), o2 = OFF(jb + 2), o3 = OFF(jb + 3);
    GATHER(jb, o0); GATHER(jb + 1, o1); GATHER(jb + 2, o2); GATHER(jb + 3, o3);
  }
  // stage the few js not yet staged (jb+12 .. i-1), then drain and consume the rest
  for (int j = jb + AHEAD; j < i; ++j) STAGE(j);
  asm volatile("s_waitcnt vmcnt(0)" ::: "memory");
  __builtin_amdgcn_sched_barrier(0);
  __builtin_amdgcn_s_barrier();
#pragma unroll 1
  for (int j = jb; j < i; ++j) { int o = OFF(j); GATHER(j, o); }

  const float* hp = h + i * Q_DIM;
  float* o = out + ((size_t)m * 256 + i) * Q_DIM;
#pragma unroll
  for (int k = 0; k < Q_DIM; ++k) o[k] = acc[k] + hp[k]; // h last: matches np order
}

extern "C" void kernel_launch(void* const* d_in, const int* in_sizes, int n_in,
                              void* d_out, int out_size, void* d_ws, size_t ws_size,
                              hipStream_t stream) {
  const float* X_oh = (const float*)d_in[0];
  const float* h    = (const float*)d_in[1];
  const float* Jm   = (const float*)d_in[2];
  float* out        = (float*)d_out;
  unsigned short* Xt = (unsigned short*)d_ws;            // 262144 B

  if (ws_size >= 262144) {
    ardca_prep<<<4096, 64, 0, stream>>>(X_oh, Xt);
    ardca_main<1><<<512, 256, 0, stream>>>(Jm, h, Xt, X_oh, out);
  } else {
    ardca_main<0><<<512, 256, 0, stream>>>(Jm, h, Xt, X_oh, out);
  }
}